// Round 4
// baseline (118.102 us; speedup 1.0000x reference)
//
#include <hip/hip_runtime.h>
#include <hip/hip_bf16.h>
#include <math.h>

#define S_LEN 2048
#define DM    1024
#define NH    16
#define DH    64
#define CHUNK 64
#define NCH   (S_LEN / CHUNK)          // 32
#define ST_STRIDE (DH * DH + DH)       // 4160 floats per (head,chunk) state

typedef __attribute__((ext_vector_type(8))) short bf16x8;   // 8 bf16 in 4 VGPRs
typedef __attribute__((ext_vector_type(4))) float f32x4;

__device__ __forceinline__ float softplus_f(float x) {
    return (x > 20.0f) ? x : log1pf(expf(x));
}

__device__ __forceinline__ ushort bf16r(float f) {   // round-to-nearest-even f32 -> bf16
    union { float f; unsigned int u; } c; c.f = f;
    unsigned int u = c.u;
    u = (u + 0x7FFFu + ((u >> 16) & 1u)) >> 16;
    return (ushort)u;
}

// ---------------- casts ----------------
__global__ __launch_bounds__(256) void cast_x_kernel(const float* __restrict__ src,
                                                     ushort* __restrict__ dst) {
    const int i = (blockIdx.x * 256 + threadIdx.x) * 4;
    const float4 v = *(const float4*)(src + i);
    ushort4 o; o.x = bf16r(v.x); o.y = bf16r(v.y); o.z = bf16r(v.z); o.w = bf16r(v.w);
    *(ushort4*)(dst + i) = o;
}

__global__ __launch_bounds__(256) void cast_w_kernel(const float* __restrict__ Wq,
                                                     const float* __restrict__ Wk,
                                                     const float* __restrict__ Wv,
                                                     const float* __restrict__ Wo,
                                                     ushort* __restrict__ dst) {
    const int y = blockIdx.y;
    const float* s = (y == 0) ? Wq : (y == 1) ? Wk : (y == 2) ? Wv : Wo;
    const int i = (blockIdx.x * 256 + threadIdx.x) * 4;
    const float4 v = *(const float4*)(s + i);
    ushort4 o; o.x = bf16r(v.x); o.y = bf16r(v.y); o.z = bf16r(v.z); o.w = bf16r(v.w);
    *(ushort4*)(dst + (size_t)y * (DM * DM) + i) = o;
}

// ---------------- bf16 MFMA GEMM core: double-buffered 2-phase + granule swizzle ----------------
// C = A @ B^T.  A: [M][1024] bf16 row-major, B: [N][1024] bf16 row-major (row = output feature).
// BM=128 x BN, BK=32, 4 waves 2x2.  LDS layout: per 16-row chunk (1KB), row r holds its four
// 16B granules permuted by g_phys = g_log ^ ((r>>1)&3) (involution).  global_load_lds dest is
// linear (rule 21); the SOURCE column is pre-swizzled; fragment reads apply the same XOR ->
// 16-lane read spreads over all 8 16B-bank-groups 2-deep (2-way = free) instead of 8-way.
template<int BN>
__device__ __forceinline__ void gemm_core(const ushort* __restrict__ A,
                                          const ushort* __restrict__ Bw,
                                          int m0, int n0,
                                          ushort* Als, ushort* Bls,
                                          f32x4 acc[4][BN / 32])
{
    constexpr int NF = BN / 32;
    constexpr int ASZ = 128 * 32;      // ushorts per A buffer
    constexpr int BSZ = BN * 32;
    const int t = threadIdx.x;
    const int w = t >> 6, l = t & 63;
    const int wr = w >> 1, wc = w & 1;

#pragma unroll
    for (int mi = 0; mi < 4; ++mi)
#pragma unroll
        for (int ni = 0; ni < NF; ++ni) acc[mi][ni] = (f32x4){0.f, 0.f, 0.f, 0.f};

    const int srow = l >> 2;                               // row within 16-row chunk
    const int scol = ((l & 3) ^ ((l >> 3) & 3)) * 8;       // inverse-swizzled source col (elems)
    const int frow = l & 15;                               // fragment row
    const int gofs = (((l >> 4) ^ ((l >> 1) & 3))) * 8;    // swizzled fragment col (elems)

    const size_t arow0 = (size_t)(m0 + w * 16 + srow) * DM + scol;
    const size_t arow1 = (size_t)(m0 + (w + 4) * 16 + srow) * DM + scol;
    const size_t brow0 = (size_t)(n0 + w * 16 + srow) * DM + scol;
    const size_t brow1 = (size_t)(n0 + (w + 4) * 16 + srow) * DM + scol;

    auto STAGE = [&](int buf, int kt) {
        ushort* Ad = Als + buf * ASZ;
        ushort* Bd = Bls + buf * BSZ;
        __builtin_amdgcn_global_load_lds(
            (const __attribute__((address_space(1))) void*)(A + arow0 + kt),
            (__attribute__((address_space(3))) void*)(Ad + w * 512), 16, 0, 0);
        __builtin_amdgcn_global_load_lds(
            (const __attribute__((address_space(1))) void*)(A + arow1 + kt),
            (__attribute__((address_space(3))) void*)(Ad + (w + 4) * 512), 16, 0, 0);
        __builtin_amdgcn_global_load_lds(
            (const __attribute__((address_space(1))) void*)(Bw + brow0 + kt),
            (__attribute__((address_space(3))) void*)(Bd + w * 512), 16, 0, 0);
        if constexpr (BN == 128) {
            __builtin_amdgcn_global_load_lds(
                (const __attribute__((address_space(1))) void*)(Bw + brow1 + kt),
                (__attribute__((address_space(3))) void*)(Bd + (w + 4) * 512), 16, 0, 0);
        }
    };

    STAGE(0, 0);
    __syncthreads();                   // buf0 staged

    int cur = 0;
#pragma unroll 2
    for (int kt = 0; kt < DM; kt += 32) {
        if (kt + 32 < DM) STAGE(cur ^ 1, kt + 32);   // prefetch next K-step (in flight over compute)

        const ushort* Ab_ = Als + cur * ASZ;
        const ushort* Bb_ = Bls + cur * BSZ;
        bf16x8 af[4], bfr[NF];
#pragma unroll
        for (int mi = 0; mi < 4; ++mi)
            af[mi] = *(const bf16x8*)&Ab_[(wr * 64 + mi * 16 + frow) * 32 + gofs];
#pragma unroll
        for (int ni = 0; ni < NF; ++ni)
            bfr[ni] = *(const bf16x8*)&Bb_[(wc * (BN / 2) + ni * 16 + frow) * 32 + gofs];
#pragma unroll
        for (int mi = 0; mi < 4; ++mi)
#pragma unroll
            for (int ni = 0; ni < NF; ++ni)
                acc[mi][ni] = __builtin_amdgcn_mfma_f32_16x16x32_bf16(af[mi], bfr[ni], acc[mi][ni], 0, 0, 0);

        __syncthreads();               // next buf staged; all waves done reading cur
        cur ^= 1;
    }
}

// Fused QKV GEMM: A=Xb [2048][1024], B=w_bf rows [0,3072) = Wq|Wk|Wv.  N=3072.
// Out z = col>>10 into head layout [(h*S+m)*DH+d], fp32; z<2: softplus(v/scale).
__global__ __launch_bounds__(256)
void qkv_gemm_kernel(const ushort* __restrict__ Xb, const ushort* __restrict__ Wqkv,
                     const float* __restrict__ bq, const float* __restrict__ bk,
                     const float* __restrict__ bv,
                     const float* __restrict__ beta,
                     float* __restrict__ qkv /* q|k|v contiguous */)
{
    __shared__ ushort Als[2 * 128 * 32];
    __shared__ ushort Bls[2 * 128 * 32];
    const int m0 = blockIdx.y * 128;
    const int n0 = blockIdx.x * 128;
    const int z  = blockIdx.x >> 3;                 // 1024-col groups
    const float* bias = (z == 0) ? bq : (z == 1) ? bk : bv;

    f32x4 acc[4][4];
    gemm_core<128>(Xb, Wqkv, m0, n0, Als, Bls, acc);

    const int t = threadIdx.x, w = t >> 6, l = t & 63;
    const int wr = w >> 1, wc = w & 1;
    float* outz = qkv + (size_t)z * (NH * S_LEN * DH);
    const int nz0 = n0 & 1023;                      // col base within this z

#pragma unroll
    for (int ni = 0; ni < 4; ++ni) {
        const int col = nz0 + wc * 64 + ni * 16 + (l & 15);
        const int h = col >> 6, d = col & 63;
        const float bcol = bias[col];
        const float inv = (z < 2) ? (1.0f / (8.0f * expf(beta[h]))) : 1.0f;
#pragma unroll
        for (int mi = 0; mi < 4; ++mi) {
            const int rbase = m0 + wr * 64 + mi * 16 + (l >> 4) * 4;
#pragma unroll
            for (int r = 0; r < 4; ++r) {
                float v = acc[mi][ni][r] + bcol;
                if (z < 2) v = softplus_f(v * inv);
                outz[((size_t)h * S_LEN + rbase + r) * DH + d] = v;
            }
        }
    }
}

// O projection: C = out_pre(bf16) @ Wo^T + bo -> fp32 [2048][1024].
__global__ __launch_bounds__(256)
void o_gemm_kernel(const ushort* __restrict__ Ab, const ushort* __restrict__ Wob,
                   const float* __restrict__ bo, float* __restrict__ out)
{
    __shared__ ushort Als[2 * 128 * 32];
    __shared__ ushort Bls[2 * 64 * 32];
    const int m0 = blockIdx.y * 128;
    const int n0 = blockIdx.x * 64;

    f32x4 acc[4][2];
    gemm_core<64>(Ab, Wob, m0, n0, Als, Bls, acc);

    const int t = threadIdx.x, w = t >> 6, l = t & 63;
    const int wr = w >> 1, wc = w & 1;
#pragma unroll
    for (int ni = 0; ni < 2; ++ni) {
        const int col = n0 + wc * 32 + ni * 16 + (l & 15);
        const float bcol = bo[col];
#pragma unroll
        for (int mi = 0; mi < 4; ++mi) {
            const int rbase = m0 + wr * 64 + mi * 16 + (l >> 4) * 4;
#pragma unroll
            for (int r = 0; r < 4; ++r)
                out[(size_t)(rbase + r) * DM + col] = acc[mi][ni][r] + bcol;
        }
    }
}

// ---------------- Pass B: per (head, chunk) state ----------------
__global__ __launch_bounds__(256)
void chunk_state_kernel(const float* __restrict__ k_ws, const float* __restrict__ v_ws,
                        float* __restrict__ st)
{
    __shared__ float Ks[64][64];
    __shared__ float Vs[64][64];
    const int c = blockIdx.x, h = blockIdx.y;
    const int t = threadIdx.x;
    const float* Kg = k_ws + ((size_t)h * S_LEN + c * CHUNK) * DH;
    const float* Vg = v_ws + ((size_t)h * S_LEN + c * CHUNK) * DH;
#pragma unroll
    for (int u = 0; u < 4; ++u) {
        int f = u * 256 + t;
        ((float4*)&Ks[0][0])[f] = ((const float4*)Kg)[f];
        ((float4*)&Vs[0][0])[f] = ((const float4*)Vg)[f];
    }
    __syncthreads();

    const int tx = t & 15, ty = t >> 4;
    float acc[4][4];
#pragma unroll
    for (int i = 0; i < 4; ++i)
#pragma unroll
        for (int j = 0; j < 4; ++j) acc[i][j] = 0.0f;

    for (int s = 0; s < 64; ++s) {
        const float4 kd = *(const float4*)&Ks[s][ty * 4];
        const float4 ve = *(const float4*)&Vs[s][tx * 4];
        const float kv[4] = {kd.x, kd.y, kd.z, kd.w};
        const float vv[4] = {ve.x, ve.y, ve.z, ve.w};
#pragma unroll
        for (int i = 0; i < 4; ++i)
#pragma unroll
            for (int j = 0; j < 4; ++j) acc[i][j] += kv[i] * vv[j];
    }
    float* base = st + (size_t)(h * NCH + c) * ST_STRIDE;
#pragma unroll
    for (int i = 0; i < 4; ++i) {
        float4 o; o.x = acc[i][0]; o.y = acc[i][1]; o.z = acc[i][2]; o.w = acc[i][3];
        *(float4*)(base + (ty * 4 + i) * 64 + tx * 4) = o;
    }
    if (t < 64) {
        float s = 0.0f;
        for (int j = 0; j < 64; ++j) s += Ks[j][t];
        base[DH * DH + t] = s;
    }
}

// ---------------- Pass C: in-place exclusive prefix scan over chunks ----------------
__global__ __launch_bounds__(64)
void scan_kernel(float* __restrict__ st)
{
    const int h = blockIdx.y;
    const int e = blockIdx.x * 64 + threadIdx.x;
    float* p = st + (size_t)h * NCH * ST_STRIDE + e;
    float acc = 0.0f;
    for (int c = 0; c < NCH; ++c) {
        const float v = p[(size_t)c * ST_STRIDE];
        p[(size_t)c * ST_STRIDE] = acc;
        acc += v;
    }
}

// ---------------- Pass D: per (head, chunk) output ----------------
__global__ __launch_bounds__(256)
void attn_out_kernel(const float* __restrict__ q_ws, const float* __restrict__ k_ws,
                     const float* __restrict__ v_ws, const float* __restrict__ pfx,
                     ushort* __restrict__ out_pre)
{
    __shared__ float QsT[64][68];   // [d][i]
    __shared__ float KsT[64][68];   // [d][j]
    __shared__ float Vs[64][64];    // [j][e]
    __shared__ float As[64][65];    // [i][j]

    const int c = blockIdx.x, h = blockIdx.y;
    const int t = threadIdx.x, tx = t & 15, ty = t >> 4;
    const size_t cbase = ((size_t)h * S_LEN + c * CHUNK) * DH;
    const float* __restrict__ pb = pfx + (size_t)(h * NCH + c) * ST_STRIDE;

#pragma unroll
    for (int u = 0; u < 4; ++u) {
        int f = u * 256 + t;
        int cg = f >> 6, row = f & 63;
        const int col4 = cg * 4;
        const float4 qv = *(const float4*)(q_ws + cbase + (size_t)row * DH + col4);
        QsT[col4 + 0][row] = qv.x;
        QsT[col4 + 1][row] = qv.y;
        QsT[col4 + 2][row] = qv.z;
        QsT[col4 + 3][row] = qv.w;
        const float4 kv = *(const float4*)(k_ws + cbase + (size_t)row * DH + col4);
        KsT[col4 + 0][row] = kv.x;
        KsT[col4 + 1][row] = kv.y;
        KsT[col4 + 2][row] = kv.z;
        KsT[col4 + 3][row] = kv.w;
    }
#pragma unroll
    for (int u = 0; u < 4; ++u) {
        int f = u * 256 + t;
        ((float4*)&Vs[0][0])[f] = ((const float4*)(v_ws + cbase))[f];
    }
    __syncthreads();

    float a[4][4];
#pragma unroll
    for (int i = 0; i < 4; ++i)
#pragma unroll
        for (int j = 0; j < 4; ++j) a[i][j] = 0.0f;
    for (int d = 0; d < 64; ++d) {
        const float4 qd = *(const float4*)&QsT[d][ty * 4];
        const float4 kd = *(const float4*)&KsT[d][tx * 4];
        const float qv[4] = {qd.x, qd.y, qd.z, qd.w};
        const float kv[4] = {kd.x, kd.y, kd.z, kd.w};
#pragma unroll
        for (int i = 0; i < 4; ++i)
#pragma unroll
            for (int j = 0; j < 4; ++j) a[i][j] += qv[i] * kv[j];
    }
#pragma unroll
    for (int i = 0; i < 4; ++i)
#pragma unroll
        for (int j = 0; j < 4; ++j) {
            const int gi = ty * 4 + i, gj = tx * 4 + j;
            As[gi][gj] = (gj <= gi) ? a[i][j] : 0.0f;
        }

    float num[4][4];
#pragma unroll
    for (int i = 0; i < 4; ++i)
#pragma unroll
        for (int j = 0; j < 4; ++j) num[i][j] = 0.0f;
    float den[4] = {0.0f, 0.0f, 0.0f, 0.0f};
#pragma unroll 4
    for (int d = 0; d < 64; ++d) {
        const float4 qd = *(const float4*)&QsT[d][ty * 4];
        const float4 pe = *(const float4*)(pb + d * 64 + tx * 4);
        const float kp = pb[DH * DH + d];
        const float qv[4] = {qd.x, qd.y, qd.z, qd.w};
        const float pv[4] = {pe.x, pe.y, pe.z, pe.w};
#pragma unroll
        for (int i = 0; i < 4; ++i) {
#pragma unroll
            for (int j = 0; j < 4; ++j) num[i][j] += qv[i] * pv[j];
            den[i] += qv[i] * kp;
        }
    }
    __syncthreads();

    float rs[4] = {0.0f, 0.0f, 0.0f, 0.0f};
    for (int j = 0; j < 64; ++j) {
        const float4 ve = *(const float4*)&Vs[j][tx * 4];
        const float vv[4] = {ve.x, ve.y, ve.z, ve.w};
#pragma unroll
        for (int i = 0; i < 4; ++i) {
            const float aij = As[ty * 4 + i][j];
            rs[i] += aij;
            num[i][0] += aij * vv[0];
            num[i][1] += aij * vv[1];
            num[i][2] += aij * vv[2];
            num[i][3] += aij * vv[3];
        }
    }

#pragma unroll
    for (int i = 0; i < 4; ++i) {
        const float dn = den[i] + rs[i];
        const float r  = 1.0f / dn;
        const int srow = c * CHUNK + ty * 4 + i;
        ushort4 o;
        o.x = bf16r(num[i][0] * r); o.y = bf16r(num[i][1] * r);
        o.z = bf16r(num[i][2] * r); o.w = bf16r(num[i][3] * r);
        *(ushort4*)(out_pre + (size_t)srow * DM + h * DH + tx * 4) = o;
    }
}

extern "C" void kernel_launch(void* const* d_in, const int* in_sizes, int n_in,
                              void* d_out, int out_size, void* d_ws, size_t ws_size,
                              hipStream_t stream)
{
    const float* x    = (const float*)d_in[0];
    const float* Wq   = (const float*)d_in[1];
    const float* bq   = (const float*)d_in[2];
    const float* Wk   = (const float*)d_in[3];
    const float* bk   = (const float*)d_in[4];
    const float* Wv   = (const float*)d_in[5];
    const float* bv   = (const float*)d_in[6];
    const float* Wo   = (const float*)d_in[7];
    const float* bo   = (const float*)d_in[8];
    const float* beta = (const float*)d_in[9];
    float* out = (float*)d_out;

    float*  q_ws  = (float*)d_ws;                          // 3 x 2M floats (q|k|v)
    float*  k_ws  = q_ws + (size_t)NH * S_LEN * DH;
    float*  v_ws  = k_ws + (size_t)NH * S_LEN * DH;
    float*  st    = v_ws + (size_t)NH * S_LEN * DH;        // 16*32*4160 floats
    ushort* x_bf  = (ushort*)(st + (size_t)NH * NCH * ST_STRIDE);   // 2M bf16
    ushort* w_bf  = x_bf + (size_t)S_LEN * DM;                      // 4 x 1M bf16 (Wq|Wk|Wv|Wo)
    ushort* op_bf = w_bf + (size_t)4 * DM * DM;                     // 2M bf16

    const ushort* wo_bf = w_bf + (size_t)3 * DM * DM;

    cast_x_kernel<<<(S_LEN * DM) / 1024, 256, 0, stream>>>(x, x_bf);
    cast_w_kernel<<<dim3((DM * DM) / 1024, 4), 256, 0, stream>>>(Wq, Wk, Wv, Wo, w_bf);

    qkv_gemm_kernel<<<dim3(3 * DM / 128, S_LEN / 128), 256, 0, stream>>>(
        x_bf, w_bf, bq, bk, bv, beta, q_ws);

    chunk_state_kernel<<<dim3(NCH, NH), 256, 0, stream>>>(k_ws, v_ws, st);
    scan_kernel<<<dim3(ST_STRIDE / 64, NH), 64, 0, stream>>>(st);
    attn_out_kernel<<<dim3(NCH, NH), 256, 0, stream>>>(q_ws, k_ws, v_ws, st, op_bf);

    o_gemm_kernel<<<dim3(DM / 64, S_LEN / 128), 256, 0, stream>>>(op_bf, wo_bf, bo, out);
}

// Round 5
// 110.821 us; speedup vs baseline: 1.0657x; 1.0657x over previous
//
#include <hip/hip_runtime.h>
#include <hip/hip_bf16.h>
#include <math.h>

#define S_LEN 2048
#define DM    1024
#define NH    16
#define DH    64
#define CHUNK 64
#define NCH   (S_LEN / CHUNK)          // 32
#define ST_STRIDE (DH * DH + DH)       // 4160 floats per (head,chunk) state

typedef __attribute__((ext_vector_type(8))) short bf16x8;   // 8 bf16 in 4 VGPRs
typedef __attribute__((ext_vector_type(4))) float f32x4;

__device__ __forceinline__ float softplus_f(float x) {
    return (x > 20.0f) ? x : log1pf(expf(x));
}

__device__ __forceinline__ ushort bf16r(float f) {   // round-to-nearest-even f32 -> bf16
    union { float f; unsigned int u; } c; c.f = f;
    unsigned int u = c.u;
    u = (u + 0x7FFFu + ((u >> 16) & 1u)) >> 16;
    return (ushort)u;
}

// ---------------- casts ----------------
__global__ __launch_bounds__(256) void cast_x_kernel(const float* __restrict__ src,
                                                     ushort* __restrict__ dst) {
    const int i = (blockIdx.x * 256 + threadIdx.x) * 4;
    const float4 v = *(const float4*)(src + i);
    ushort4 o; o.x = bf16r(v.x); o.y = bf16r(v.y); o.z = bf16r(v.z); o.w = bf16r(v.w);
    *(ushort4*)(dst + i) = o;
}

__global__ __launch_bounds__(256) void cast_w_kernel(const float* __restrict__ Wq,
                                                     const float* __restrict__ Wk,
                                                     const float* __restrict__ Wv,
                                                     const float* __restrict__ Wo,
                                                     ushort* __restrict__ dst) {
    const int y = blockIdx.y;
    const float* s = (y == 0) ? Wq : (y == 1) ? Wk : (y == 2) ? Wv : Wo;
    const int i = (blockIdx.x * 256 + threadIdx.x) * 4;
    const float4 v = *(const float4*)(s + i);
    ushort4 o; o.x = bf16r(v.x); o.y = bf16r(v.y); o.z = bf16r(v.z); o.w = bf16r(v.w);
    *(ushort4*)(dst + (size_t)y * (DM * DM) + i) = o;
}

// ---------------- bf16 MFMA GEMM core: 8-wave, single-buffer, granule swizzle ----------------
// C = A @ B^T.  A: [M][1024] bf16 row-major, B: [N][1024] bf16 row-major (row = output feature).
// BM=128 x BN, BK=32.  WR x WC waves (512 threads), wave sub-tile (128/WR) x (BN/WC).
// LDS: per 16-row chunk (1KB), row r's four 16B granules permuted g_phys = g_log ^ ((r>>1)&3)
// (involution; rule 21: linear gload_lds dest + inverse-swizzled global SOURCE col + swizzled
// fragment read) -> verified 0 bank conflicts (R4 profile), coalescing intact (same 64B lines).
template<int BN, int WR, int WC>
__device__ __forceinline__ void gemm_core(const ushort* __restrict__ A,
                                          const ushort* __restrict__ Bw,
                                          int m0, int n0,
                                          ushort* Als, ushort* Bls,
                                          f32x4 acc[128 / (WR * 16)][BN / (WC * 16)])
{
    constexpr int MF = 128 / (WR * 16);
    constexpr int NF = BN / (WC * 16);
    const int t = threadIdx.x;
    const int w = t >> 6, l = t & 63;
    const int wr = w / WC, wc = w % WC;

#pragma unroll
    for (int mi = 0; mi < MF; ++mi)
#pragma unroll
        for (int ni = 0; ni < NF; ++ni) acc[mi][ni] = (f32x4){0.f, 0.f, 0.f, 0.f};

    const int srow = l >> 2;                               // row within 16-row chunk
    const int scol = ((l & 3) ^ ((l >> 3) & 3)) * 8;       // inverse-swizzled source col (elems)
    const int frow = l & 15;                               // fragment row
    const int gofs = ((l >> 4) ^ ((l >> 1) & 3)) * 8;      // swizzled fragment col (elems)

    const size_t arow = (size_t)(m0 + w * 16 + srow) * DM + scol;   // wave w stages A chunk w
    const size_t brow = (size_t)(n0 + w * 16 + srow) * DM + scol;   // and B chunk w (if < BN/16)

    for (int kt = 0; kt < DM; kt += 32) {
        __builtin_amdgcn_global_load_lds(
            (const __attribute__((address_space(1))) void*)(A + arow + kt),
            (__attribute__((address_space(3))) void*)(Als + w * 512), 16, 0, 0);
        if (w * 16 < BN) {
            __builtin_amdgcn_global_load_lds(
                (const __attribute__((address_space(1))) void*)(Bw + brow + kt),
                (__attribute__((address_space(3))) void*)(Bls + w * 512), 16, 0, 0);
        }
        __syncthreads();   // drains vmcnt -> staged data visible

        bf16x8 af[MF], bfr[NF];
#pragma unroll
        for (int mi = 0; mi < MF; ++mi)
            af[mi] = *(const bf16x8*)&Als[(wr * (128 / WR) + mi * 16 + frow) * 32 + gofs];
#pragma unroll
        for (int ni = 0; ni < NF; ++ni)
            bfr[ni] = *(const bf16x8*)&Bls[(wc * (BN / WC) + ni * 16 + frow) * 32 + gofs];
#pragma unroll
        for (int mi = 0; mi < MF; ++mi)
#pragma unroll
            for (int ni = 0; ni < NF; ++ni)
                acc[mi][ni] = __builtin_amdgcn_mfma_f32_16x16x32_bf16(af[mi], bfr[ni], acc[mi][ni], 0, 0, 0);

        __syncthreads();   // protect LDS before next stage
    }
}

// Fused QKV GEMM: A=Xb [2048][1024], B=w_bf rows [0,3072) = Wq|Wk|Wv.  N=3072.
// 1D grid of 384 tiles, XCD-swizzled (384%8==0).  512 threads, 2x4 waves.
__global__ __launch_bounds__(512)
void qkv_gemm_kernel(const ushort* __restrict__ Xb, const ushort* __restrict__ Wqkv,
                     const float* __restrict__ bq, const float* __restrict__ bk,
                     const float* __restrict__ bv,
                     const float* __restrict__ beta,
                     float* __restrict__ qkv /* q|k|v contiguous */)
{
    __shared__ ushort Als[128 * 32];
    __shared__ ushort Bls[128 * 32];
    const int b = blockIdx.x;
    const int logical = (b & 7) * 48 + (b >> 3);   // XCD x owns 48 consecutive logical tiles
    const int mb = logical & 15, nb = logical >> 4;   // m-fastest: A-panel stream stays in XCD L2
    const int m0 = mb * 128;
    const int n0 = nb * 128;
    const int z  = nb >> 3;                        // 0:q 1:k 2:v
    const float* bias = (z == 0) ? bq : (z == 1) ? bk : bv;

    f32x4 acc[4][2];
    gemm_core<128, 2, 4>(Xb, Wqkv, m0, n0, Als, Bls, acc);

    const int t = threadIdx.x, w = t >> 6, l = t & 63;
    const int wr = w >> 2, wc = w & 3;
    float* outz = qkv + (size_t)z * (NH * S_LEN * DH);
    const int nz0 = n0 & 1023;                     // col base within this z

#pragma unroll
    for (int ni = 0; ni < 2; ++ni) {
        const int col = nz0 + wc * 32 + ni * 16 + (l & 15);
        const int h = col >> 6, d = col & 63;
        const float bcol = bias[col];
        const float inv = (z < 2) ? (1.0f / (8.0f * expf(beta[h]))) : 1.0f;
#pragma unroll
        for (int mi = 0; mi < 4; ++mi) {
            const int rbase = m0 + wr * 64 + mi * 16 + (l >> 4) * 4;
#pragma unroll
            for (int r = 0; r < 4; ++r) {
                float v = acc[mi][ni][r] + bcol;
                if (z < 2) v = softplus_f(v * inv);
                outz[((size_t)h * S_LEN + rbase + r) * DH + d] = v;
            }
        }
    }
}

// O projection: C = out_pre(bf16) @ Wo^T + bo -> fp32 [2048][1024].  256 tiles, XCD-swizzled.
__global__ __launch_bounds__(512)
void o_gemm_kernel(const ushort* __restrict__ Ab, const ushort* __restrict__ Wob,
                   const float* __restrict__ bo, float* __restrict__ out)
{
    __shared__ ushort Als[128 * 32];
    __shared__ ushort Bls[64 * 32];
    const int b = blockIdx.x;
    const int logical = (b & 7) * 32 + (b >> 3);
    const int mb = logical & 15, nb = logical >> 4;   // nb in [0,16)
    const int m0 = mb * 128;
    const int n0 = nb * 64;

    f32x4 acc[4][1];
    gemm_core<64, 2, 4>(Ab, Wob, m0, n0, Als, Bls, acc);

    const int t = threadIdx.x, w = t >> 6, l = t & 63;
    const int wr = w >> 2, wc = w & 3;
    const int col = n0 + wc * 16 + (l & 15);
    const float bcol = bo[col];
#pragma unroll
    for (int mi = 0; mi < 4; ++mi) {
        const int rbase = m0 + wr * 64 + mi * 16 + (l >> 4) * 4;
#pragma unroll
        for (int r = 0; r < 4; ++r)
            out[(size_t)(rbase + r) * DM + col] = acc[mi][0][r] + bcol;
    }
}

// ---------------- Pass B: per (head, chunk) state ----------------
__global__ __launch_bounds__(256)
void chunk_state_kernel(const float* __restrict__ k_ws, const float* __restrict__ v_ws,
                        float* __restrict__ st)
{
    __shared__ float Ks[64][64];
    __shared__ float Vs[64][64];
    const int c = blockIdx.x, h = blockIdx.y;
    const int t = threadIdx.x;
    const float* Kg = k_ws + ((size_t)h * S_LEN + c * CHUNK) * DH;
    const float* Vg = v_ws + ((size_t)h * S_LEN + c * CHUNK) * DH;
#pragma unroll
    for (int u = 0; u < 4; ++u) {
        int f = u * 256 + t;
        ((float4*)&Ks[0][0])[f] = ((const float4*)Kg)[f];
        ((float4*)&Vs[0][0])[f] = ((const float4*)Vg)[f];
    }
    __syncthreads();

    const int tx = t & 15, ty = t >> 4;
    float acc[4][4];
#pragma unroll
    for (int i = 0; i < 4; ++i)
#pragma unroll
        for (int j = 0; j < 4; ++j) acc[i][j] = 0.0f;

    for (int s = 0; s < 64; ++s) {
        const float4 kd = *(const float4*)&Ks[s][ty * 4];
        const float4 ve = *(const float4*)&Vs[s][tx * 4];
        const float kv[4] = {kd.x, kd.y, kd.z, kd.w};
        const float vv[4] = {ve.x, ve.y, ve.z, ve.w};
#pragma unroll
        for (int i = 0; i < 4; ++i)
#pragma unroll
            for (int j = 0; j < 4; ++j) acc[i][j] += kv[i] * vv[j];
    }
    float* base = st + (size_t)(h * NCH + c) * ST_STRIDE;
#pragma unroll
    for (int i = 0; i < 4; ++i) {
        float4 o; o.x = acc[i][0]; o.y = acc[i][1]; o.z = acc[i][2]; o.w = acc[i][3];
        *(float4*)(base + (ty * 4 + i) * 64 + tx * 4) = o;
    }
    if (t < 64) {
        float s = 0.0f;
        for (int j = 0; j < 64; ++j) s += Ks[j][t];
        base[DH * DH + t] = s;
    }
}

// ---------------- Pass C: in-place exclusive prefix scan over chunks ----------------
__global__ __launch_bounds__(64)
void scan_kernel(float* __restrict__ st)
{
    const int h = blockIdx.y;
    const int e = blockIdx.x * 64 + threadIdx.x;
    float* p = st + (size_t)h * NCH * ST_STRIDE + e;
    float acc = 0.0f;
    for (int c = 0; c < NCH; ++c) {
        const float v = p[(size_t)c * ST_STRIDE];
        p[(size_t)c * ST_STRIDE] = acc;
        acc += v;
    }
}

// ---------------- Pass D: per (head, chunk) output ----------------
__global__ __launch_bounds__(256)
void attn_out_kernel(const float* __restrict__ q_ws, const float* __restrict__ k_ws,
                     const float* __restrict__ v_ws, const float* __restrict__ pfx,
                     ushort* __restrict__ out_pre)
{
    __shared__ float QsT[64][68];   // [d][i]
    __shared__ float KsT[64][68];   // [d][j]
    __shared__ float Vs[64][64];    // [j][e]
    __shared__ float As[64][65];    // [i][j]

    const int c = blockIdx.x, h = blockIdx.y;
    const int t = threadIdx.x, tx = t & 15, ty = t >> 4;
    const size_t cbase = ((size_t)h * S_LEN + c * CHUNK) * DH;
    const float* __restrict__ pb = pfx + (size_t)(h * NCH + c) * ST_STRIDE;

#pragma unroll
    for (int u = 0; u < 4; ++u) {
        int f = u * 256 + t;
        int cg = f >> 6, row = f & 63;
        const int col4 = cg * 4;
        const float4 qv = *(const float4*)(q_ws + cbase + (size_t)row * DH + col4);
        QsT[col4 + 0][row] = qv.x;
        QsT[col4 + 1][row] = qv.y;
        QsT[col4 + 2][row] = qv.z;
        QsT[col4 + 3][row] = qv.w;
        const float4 kv = *(const float4*)(k_ws + cbase + (size_t)row * DH + col4);
        KsT[col4 + 0][row] = kv.x;
        KsT[col4 + 1][row] = kv.y;
        KsT[col4 + 2][row] = kv.z;
        KsT[col4 + 3][row] = kv.w;
    }
#pragma unroll
    for (int u = 0; u < 4; ++u) {
        int f = u * 256 + t;
        ((float4*)&Vs[0][0])[f] = ((const float4*)(v_ws + cbase))[f];
    }
    __syncthreads();

    float a[4][4];
#pragma unroll
    for (int i = 0; i < 4; ++i)
#pragma unroll
        for (int j = 0; j < 4; ++j) a[i][j] = 0.0f;
    for (int d = 0; d < 64; ++d) {
        const float4 qd = *(const float4*)&QsT[d][ty * 4];
        const float4 kd = *(const float4*)&KsT[d][tx * 4];
        const float qv[4] = {qd.x, qd.y, qd.z, qd.w};
        const float kv[4] = {kd.x, kd.y, kd.z, kd.w};
#pragma unroll
        for (int i = 0; i < 4; ++i)
#pragma unroll
            for (int j = 0; j < 4; ++j) a[i][j] += qv[i] * kv[j];
    }
#pragma unroll
    for (int i = 0; i < 4; ++i)
#pragma unroll
        for (int j = 0; j < 4; ++j) {
            const int gi = ty * 4 + i, gj = tx * 4 + j;
            As[gi][gj] = (gj <= gi) ? a[i][j] : 0.0f;
        }

    float num[4][4];
#pragma unroll
    for (int i = 0; i < 4; ++i)
#pragma unroll
        for (int j = 0; j < 4; ++j) num[i][j] = 0.0f;
    float den[4] = {0.0f, 0.0f, 0.0f, 0.0f};
#pragma unroll 4
    for (int d = 0; d < 64; ++d) {
        const float4 qd = *(const float4*)&QsT[d][ty * 4];
        const float4 pe = *(const float4*)(pb + d * 64 + tx * 4);
        const float kp = pb[DH * DH + d];
        const float qv[4] = {qd.x, qd.y, qd.z, qd.w};
        const float pv[4] = {pe.x, pe.y, pe.z, pe.w};
#pragma unroll
        for (int i = 0; i < 4; ++i) {
#pragma unroll
            for (int j = 0; j < 4; ++j) num[i][j] += qv[i] * pv[j];
            den[i] += qv[i] * kp;
        }
    }
    __syncthreads();

    float rs[4] = {0.0f, 0.0f, 0.0f, 0.0f};
    for (int j = 0; j < 64; ++j) {
        const float4 ve = *(const float4*)&Vs[j][tx * 4];
        const float vv[4] = {ve.x, ve.y, ve.z, ve.w};
#pragma unroll
        for (int i = 0; i < 4; ++i) {
            const float aij = As[ty * 4 + i][j];
            rs[i] += aij;
            num[i][0] += aij * vv[0];
            num[i][1] += aij * vv[1];
            num[i][2] += aij * vv[2];
            num[i][3] += aij * vv[3];
        }
    }

#pragma unroll
    for (int i = 0; i < 4; ++i) {
        const float dn = den[i] + rs[i];
        const float r  = 1.0f / dn;
        const int srow = c * CHUNK + ty * 4 + i;
        ushort4 o;
        o.x = bf16r(num[i][0] * r); o.y = bf16r(num[i][1] * r);
        o.z = bf16r(num[i][2] * r); o.w = bf16r(num[i][3] * r);
        *(ushort4*)(out_pre + (size_t)srow * DM + h * DH + tx * 4) = o;
    }
}

extern "C" void kernel_launch(void* const* d_in, const int* in_sizes, int n_in,
                              void* d_out, int out_size, void* d_ws, size_t ws_size,
                              hipStream_t stream)
{
    const float* x    = (const float*)d_in[0];
    const float* Wq   = (const float*)d_in[1];
    const float* bq   = (const float*)d_in[2];
    const float* Wk   = (const float*)d_in[3];
    const float* bk   = (const float*)d_in[4];
    const float* Wv   = (const float*)d_in[5];
    const float* bv   = (const float*)d_in[6];
    const float* Wo   = (const float*)d_in[7];
    const float* bo   = (const float*)d_in[8];
    const float* beta = (const float*)d_in[9];
    float* out = (float*)d_out;

    float*  q_ws  = (float*)d_ws;                          // 3 x 2M floats (q|k|v)
    float*  k_ws  = q_ws + (size_t)NH * S_LEN * DH;
    float*  v_ws  = k_ws + (size_t)NH * S_LEN * DH;
    float*  st    = v_ws + (size_t)NH * S_LEN * DH;        // 16*32*4160 floats
    ushort* x_bf  = (ushort*)(st + (size_t)NH * NCH * ST_STRIDE);   // 2M bf16
    ushort* w_bf  = x_bf + (size_t)S_LEN * DM;                      // 4 x 1M bf16 (Wq|Wk|Wv|Wo)
    ushort* op_bf = w_bf + (size_t)4 * DM * DM;                     // 2M bf16

    const ushort* wo_bf = w_bf + (size_t)3 * DM * DM;

    cast_x_kernel<<<(S_LEN * DM) / 1024, 256, 0, stream>>>(x, x_bf);
    cast_w_kernel<<<dim3((DM * DM) / 1024, 4), 256, 0, stream>>>(Wq, Wk, Wv, Wo, w_bf);

    qkv_gemm_kernel<<<384, 512, 0, stream>>>(x_bf, w_bf, bq, bk, bv, beta, q_ws);

    chunk_state_kernel<<<dim3(NCH, NH), 256, 0, stream>>>(k_ws, v_ws, st);
    scan_kernel<<<dim3(ST_STRIDE / 64, NH), 64, 0, stream>>>(st);
    attn_out_kernel<<<dim3(NCH, NH), 256, 0, stream>>>(q_ws, k_ws, v_ws, st, op_bf);

    o_gemm_kernel<<<256, 512, 0, stream>>>(op_bf, wo_bf, bo, out);
}

// Round 6
// 108.539 us; speedup vs baseline: 1.0881x; 1.0210x over previous
//
#include <hip/hip_runtime.h>
#include <hip/hip_bf16.h>
#include <math.h>

#define S_LEN 2048
#define DM    1024
#define NH    16
#define DH    64
#define CHUNK 64
#define NCH   (S_LEN / CHUNK)          // 32
#define ST_STRIDE (DH * DH + DH)       // 4160 floats per (head,chunk) state

typedef __attribute__((ext_vector_type(8))) short bf16x8;   // 8 bf16 in 4 VGPRs
typedef __attribute__((ext_vector_type(4))) float f32x4;

__device__ __forceinline__ float softplus_f(float x) {
    return (x > 20.0f) ? x : log1pf(expf(x));
}

__device__ __forceinline__ ushort bf16r(float f) {   // round-to-nearest-even f32 -> bf16
    union { float f; unsigned int u; } c; c.f = f;
    unsigned int u = c.u;
    u = (u + 0x7FFFu + ((u >> 16) & 1u)) >> 16;
    return (ushort)u;
}

// ---------------- casts ----------------
__global__ __launch_bounds__(256) void cast_x_kernel(const float* __restrict__ src,
                                                     ushort* __restrict__ dst) {
    const int i = (blockIdx.x * 256 + threadIdx.x) * 4;
    const float4 v = *(const float4*)(src + i);
    ushort4 o; o.x = bf16r(v.x); o.y = bf16r(v.y); o.z = bf16r(v.z); o.w = bf16r(v.w);
    *(ushort4*)(dst + i) = o;
}

__global__ __launch_bounds__(256) void cast_w_kernel(const float* __restrict__ Wq,
                                                     const float* __restrict__ Wk,
                                                     const float* __restrict__ Wv,
                                                     const float* __restrict__ Wo,
                                                     ushort* __restrict__ dst) {
    const int y = blockIdx.y;
    const float* s = (y == 0) ? Wq : (y == 1) ? Wk : (y == 2) ? Wv : Wo;
    const int i = (blockIdx.x * 256 + threadIdx.x) * 4;
    const float4 v = *(const float4*)(s + i);
    ushort4 o; o.x = bf16r(v.x); o.y = bf16r(v.y); o.z = bf16r(v.z); o.w = bf16r(v.w);
    *(ushort4*)(dst + (size_t)y * (DM * DM) + i) = o;
}

// ---------------- bf16 MFMA GEMM core: depth-2 counted-vmcnt pipeline + granule swizzle ----
// C = A @ B^T.  A: [M][1024] bf16 row-major, B: [N][1024] bf16 row-major (row = output feat).
// BM=128 x BN, BK=32.  WRxWC waves, wave sub-tile (128/WR) x (BN/WC).
// Swizzle (verified 0-conflict, R4/R5): per 16-row 1KB chunk, row r's four 16B granules
// permuted g_phys = g_log ^ ((r>>1)&3); linear gload_lds dest + inverse-swizzled global
// source col + swizzled fragment read (rule 21).
// Pipeline (T3+T4 minimum): 2 LDS buffers; stage tile t+2 after the barrier that retires
// tile t; in-loop wait is counted vmcnt(LPW) (own tile's loads only) + raw s_barrier --
// never vmcnt(0) except the last iteration.  Loads get a full iteration of flight time.
template<int BN, int WR, int WC>
__device__ __forceinline__ void gemm_core(const ushort* __restrict__ A,
                                          const ushort* __restrict__ Bw,
                                          int m0, int n0,
                                          ushort* Als, ushort* Bls,
                                          f32x4 acc[128 / (WR * 16)][BN / (WC * 16)])
{
    constexpr int MF  = 128 / (WR * 16);
    constexpr int NF  = BN / (WC * 16);
    constexpr int NW  = WR * WC;
    constexpr int ASZ = 128 * 32;          // ushorts per A buffer
    constexpr int BSZ = BN * 32;
    constexpr int LPW = (8 + BN / 16) / NW; // gload_lds per wave per tile (uniform)
    constexpr int NT  = DM / 32;           // 32 K-steps

    const int t = threadIdx.x;
    const int w = t >> 6, l = t & 63;
    const int wr = w / WC, wc = w % WC;

#pragma unroll
    for (int mi = 0; mi < MF; ++mi)
#pragma unroll
        for (int ni = 0; ni < NF; ++ni) acc[mi][ni] = (f32x4){0.f, 0.f, 0.f, 0.f};

    const int srow = l >> 2;                               // row within 16-row chunk
    const int scol = ((l & 3) ^ ((l >> 3) & 3)) * 8;       // inverse-swizzled source col
    const int frow = l & 15;                               // fragment row
    const int gofs = ((l >> 4) ^ ((l >> 1) & 3)) * 8;      // swizzled fragment col

    auto STAGE = [&](int buf, int kt) {
        ushort* Ad = Als + buf * ASZ;
        ushort* Bd = Bls + buf * BSZ;
        if constexpr (NW == 8) {           // 8 A-chunks + 8 B-chunks, 1+1 per wave
            __builtin_amdgcn_global_load_lds(
                (const __attribute__((address_space(1))) void*)(A + (size_t)(m0 + w * 16 + srow) * DM + kt + scol),
                (__attribute__((address_space(3))) void*)(Ad + w * 512), 16, 0, 0);
            __builtin_amdgcn_global_load_lds(
                (const __attribute__((address_space(1))) void*)(Bw + (size_t)(n0 + w * 16 + srow) * DM + kt + scol),
                (__attribute__((address_space(3))) void*)(Bd + w * 512), 16, 0, 0);
        } else {                           // NW==4, BN==64: 2 A-chunks + 1 B-chunk per wave
            __builtin_amdgcn_global_load_lds(
                (const __attribute__((address_space(1))) void*)(A + (size_t)(m0 + w * 16 + srow) * DM + kt + scol),
                (__attribute__((address_space(3))) void*)(Ad + w * 512), 16, 0, 0);
            __builtin_amdgcn_global_load_lds(
                (const __attribute__((address_space(1))) void*)(A + (size_t)(m0 + (w + 4) * 16 + srow) * DM + kt + scol),
                (__attribute__((address_space(3))) void*)(Ad + (w + 4) * 512), 16, 0, 0);
            __builtin_amdgcn_global_load_lds(
                (const __attribute__((address_space(1))) void*)(Bw + (size_t)(n0 + w * 16 + srow) * DM + kt + scol),
                (__attribute__((address_space(3))) void*)(Bd + w * 512), 16, 0, 0);
        }
    };

    STAGE(0, 0);
    STAGE(1, 32);

    int cur = 0;
    for (int tt = 0; tt < NT; ++tt) {
        // wait for THIS tile's loads only (counted); vmcnt(0) only on the final iteration
        if (tt + 1 < NT) asm volatile("s_waitcnt vmcnt(%0)" :: "i"(LPW) : "memory");
        else             asm volatile("s_waitcnt vmcnt(0)" ::: "memory");
        __builtin_amdgcn_s_barrier();          // all waves' tile-tt loads landed
        asm volatile("" ::: "memory");         // no ds_read hoists above the barrier

        const ushort* Ab_ = Als + cur * ASZ;
        const ushort* Bb_ = Bls + cur * BSZ;
        bf16x8 af[MF], bfr[NF];
#pragma unroll
        for (int mi = 0; mi < MF; ++mi)
            af[mi] = *(const bf16x8*)&Ab_[(wr * (128 / WR) + mi * 16 + frow) * 32 + gofs];
#pragma unroll
        for (int ni = 0; ni < NF; ++ni)
            bfr[ni] = *(const bf16x8*)&Bb_[(wc * (BN / WC) + ni * 16 + frow) * 32 + gofs];
#pragma unroll
        for (int mi = 0; mi < MF; ++mi)
#pragma unroll
            for (int ni = 0; ni < NF; ++ni)
                acc[mi][ni] = __builtin_amdgcn_mfma_f32_16x16x32_bf16(af[mi], bfr[ni], acc[mi][ni], 0, 0, 0);

        asm volatile("" ::: "memory");         // ds_reads retired before barrier
        __builtin_amdgcn_s_barrier();          // all waves done reading buf[cur]
        asm volatile("" ::: "memory");         // STAGE stays below the barrier
        if (tt + 2 < NT) STAGE(cur, (tt + 2) * 32);
        cur ^= 1;
    }
}

// Fused QKV GEMM: A=Xb [2048][1024], B=w_bf rows [0,3072) = Wq|Wk|Wv.  N=3072.
// 384 tiles XCD-swizzled; 512 threads, 2x4 waves; depth-2 pipeline (vmcnt(2) steady).
__global__ __launch_bounds__(512)
void qkv_gemm_kernel(const ushort* __restrict__ Xb, const ushort* __restrict__ Wqkv,
                     const float* __restrict__ bq, const float* __restrict__ bk,
                     const float* __restrict__ bv,
                     const float* __restrict__ beta,
                     float* __restrict__ qkv /* q|k|v contiguous */)
{
    __shared__ ushort Als[2 * 128 * 32];
    __shared__ ushort Bls[2 * 128 * 32];
    const int b = blockIdx.x;
    const int logical = (b & 7) * 48 + (b >> 3);   // XCD x owns 48 consecutive logical tiles
    const int mb = logical & 15, nb = logical >> 4;
    const int m0 = mb * 128;
    const int n0 = nb * 128;
    const int z  = nb >> 3;                        // 0:q 1:k 2:v
    const float* bias = (z == 0) ? bq : (z == 1) ? bk : bv;

    f32x4 acc[4][2];
    gemm_core<128, 2, 4>(Xb, Wqkv, m0, n0, Als, Bls, acc);

    const int t = threadIdx.x, w = t >> 6, l = t & 63;
    const int wr = w >> 2, wc = w & 3;
    float* outz = qkv + (size_t)z * (NH * S_LEN * DH);
    const int nz0 = n0 & 1023;

#pragma unroll
    for (int ni = 0; ni < 2; ++ni) {
        const int col = nz0 + wc * 32 + ni * 16 + (l & 15);
        const int h = col >> 6, d = col & 63;
        const float bcol = bias[col];
        const float inv = (z < 2) ? (1.0f / (8.0f * expf(beta[h]))) : 1.0f;
#pragma unroll
        for (int mi = 0; mi < 4; ++mi) {
            const int rbase = m0 + wr * 64 + mi * 16 + (l >> 4) * 4;
#pragma unroll
            for (int r = 0; r < 4; ++r) {
                float v = acc[mi][ni][r] + bcol;
                if (z < 2) v = softplus_f(v * inv);
                outz[((size_t)h * S_LEN + rbase + r) * DH + d] = v;
            }
        }
    }
}

// O projection: C = out_pre(bf16) @ Wo^T + bo -> fp32 [2048][1024].
// 256 tiles XCD-swizzled; 256 threads, 2x2 waves; depth-2 pipeline (vmcnt(3) steady).
__global__ __launch_bounds__(256)
void o_gemm_kernel(const ushort* __restrict__ Ab, const ushort* __restrict__ Wob,
                   const float* __restrict__ bo, float* __restrict__ out)
{
    __shared__ ushort Als[2 * 128 * 32];
    __shared__ ushort Bls[2 * 64 * 32];
    const int b = blockIdx.x;
    const int logical = (b & 7) * 32 + (b >> 3);
    const int mb = logical & 15, nb = logical >> 4;   // nb in [0,16)
    const int m0 = mb * 128;
    const int n0 = nb * 64;

    f32x4 acc[4][2];
    gemm_core<64, 2, 2>(Ab, Wob, m0, n0, Als, Bls, acc);

    const int t = threadIdx.x, w = t >> 6, l = t & 63;
    const int wr = w >> 1, wc = w & 1;
#pragma unroll
    for (int ni = 0; ni < 2; ++ni) {
        const int col = n0 + wc * 32 + ni * 16 + (l & 15);
        const float bcol = bo[col];
#pragma unroll
        for (int mi = 0; mi < 4; ++mi) {
            const int rbase = m0 + wr * 64 + mi * 16 + (l >> 4) * 4;
#pragma unroll
            for (int r = 0; r < 4; ++r)
                out[(size_t)(rbase + r) * DM + col] = acc[mi][ni][r] + bcol;
        }
    }
}

// ---------------- Pass B: per (head, chunk) state ----------------
__global__ __launch_bounds__(256)
void chunk_state_kernel(const float* __restrict__ k_ws, const float* __restrict__ v_ws,
                        float* __restrict__ st)
{
    __shared__ float Ks[64][64];
    __shared__ float Vs[64][64];
    const int c = blockIdx.x, h = blockIdx.y;
    const int t = threadIdx.x;
    const float* Kg = k_ws + ((size_t)h * S_LEN + c * CHUNK) * DH;
    const float* Vg = v_ws + ((size_t)h * S_LEN + c * CHUNK) * DH;
#pragma unroll
    for (int u = 0; u < 4; ++u) {
        int f = u * 256 + t;
        ((float4*)&Ks[0][0])[f] = ((const float4*)Kg)[f];
        ((float4*)&Vs[0][0])[f] = ((const float4*)Vg)[f];
    }
    __syncthreads();

    const int tx = t & 15, ty = t >> 4;
    float acc[4][4];
#pragma unroll
    for (int i = 0; i < 4; ++i)
#pragma unroll
        for (int j = 0; j < 4; ++j) acc[i][j] = 0.0f;

    for (int s = 0; s < 64; ++s) {
        const float4 kd = *(const float4*)&Ks[s][ty * 4];
        const float4 ve = *(const float4*)&Vs[s][tx * 4];
        const float kv[4] = {kd.x, kd.y, kd.z, kd.w};
        const float vv[4] = {ve.x, ve.y, ve.z, ve.w};
#pragma unroll
        for (int i = 0; i < 4; ++i)
#pragma unroll
            for (int j = 0; j < 4; ++j) acc[i][j] += kv[i] * vv[j];
    }
    float* base = st + (size_t)(h * NCH + c) * ST_STRIDE;
#pragma unroll
    for (int i = 0; i < 4; ++i) {
        float4 o; o.x = acc[i][0]; o.y = acc[i][1]; o.z = acc[i][2]; o.w = acc[i][3];
        *(float4*)(base + (ty * 4 + i) * 64 + tx * 4) = o;
    }
    if (t < 64) {
        float s = 0.0f;
        for (int j = 0; j < 64; ++j) s += Ks[j][t];
        base[DH * DH + t] = s;
    }
}

// ---------------- Pass C: in-place exclusive prefix scan over chunks ----------------
__global__ __launch_bounds__(64)
void scan_kernel(float* __restrict__ st)
{
    const int h = blockIdx.y;
    const int e = blockIdx.x * 64 + threadIdx.x;
    float* p = st + (size_t)h * NCH * ST_STRIDE + e;
    float acc = 0.0f;
    for (int c = 0; c < NCH; ++c) {
        const float v = p[(size_t)c * ST_STRIDE];
        p[(size_t)c * ST_STRIDE] = acc;
        acc += v;
    }
}

// ---------------- Pass D: per (head, chunk) output ----------------
__global__ __launch_bounds__(256)
void attn_out_kernel(const float* __restrict__ q_ws, const float* __restrict__ k_ws,
                     const float* __restrict__ v_ws, const float* __restrict__ pfx,
                     ushort* __restrict__ out_pre)
{
    __shared__ float QsT[64][68];   // [d][i]
    __shared__ float KsT[64][68];   // [d][j]
    __shared__ float Vs[64][64];    // [j][e]
    __shared__ float As[64][65];    // [i][j]

    const int c = blockIdx.x, h = blockIdx.y;
    const int t = threadIdx.x, tx = t & 15, ty = t >> 4;
    const size_t cbase = ((size_t)h * S_LEN + c * CHUNK) * DH;
    const float* __restrict__ pb = pfx + (size_t)(h * NCH + c) * ST_STRIDE;

#pragma unroll
    for (int u = 0; u < 4; ++u) {
        int f = u * 256 + t;
        int cg = f >> 6, row = f & 63;
        const int col4 = cg * 4;
        const float4 qv = *(const float4*)(q_ws + cbase + (size_t)row * DH + col4);
        QsT[col4 + 0][row] = qv.x;
        QsT[col4 + 1][row] = qv.y;
        QsT[col4 + 2][row] = qv.z;
        QsT[col4 + 3][row] = qv.w;
        const float4 kv = *(const float4*)(k_ws + cbase + (size_t)row * DH + col4);
        KsT[col4 + 0][row] = kv.x;
        KsT[col4 + 1][row] = kv.y;
        KsT[col4 + 2][row] = kv.z;
        KsT[col4 + 3][row] = kv.w;
    }
#pragma unroll
    for (int u = 0; u < 4; ++u) {
        int f = u * 256 + t;
        ((float4*)&Vs[0][0])[f] = ((const float4*)(v_ws + cbase))[f];
    }
    __syncthreads();

    float a[4][4];
#pragma unroll
    for (int i = 0; i < 4; ++i)
#pragma unroll
        for (int j = 0; j < 4; ++j) a[i][j] = 0.0f;
    for (int d = 0; d < 64; ++d) {
        const float4 qd = *(const float4*)&QsT[d][ty * 4];
        const float4 kd = *(const float4*)&KsT[d][tx * 4];
        const float qv[4] = {qd.x, qd.y, qd.z, qd.w};
        const float kv[4] = {kd.x, kd.y, kd.z, kd.w};
#pragma unroll
        for (int i = 0; i < 4; ++i)
#pragma unroll
            for (int j = 0; j < 4; ++j) a[i][j] += qv[i] * kv[j];
    }
#pragma unroll
    for (int i = 0; i < 4; ++i)
#pragma unroll
        for (int j = 0; j < 4; ++j) {
            const int gi = ty * 4 + i, gj = tx * 4 + j;
            As[gi][gj] = (gj <= gi) ? a[i][j] : 0.0f;
        }

    float num[4][4];
#pragma unroll
    for (int i = 0; i < 4; ++i)
#pragma unroll
        for (int j = 0; j < 4; ++j) num[i][j] = 0.0f;
    float den[4] = {0.0f, 0.0f, 0.0f, 0.0f};
#pragma unroll 4
    for (int d = 0; d < 64; ++d) {
        const float4 qd = *(const float4*)&QsT[d][ty * 4];
        const float4 pe = *(const float4*)(pb + d * 64 + tx * 4);
        const float kp = pb[DH * DH + d];
        const float qv[4] = {qd.x, qd.y, qd.z, qd.w};
        const float pv[4] = {pe.x, pe.y, pe.z, pe.w};
#pragma unroll
        for (int i = 0; i < 4; ++i) {
#pragma unroll
            for (int j = 0; j < 4; ++j) num[i][j] += qv[i] * pv[j];
            den[i] += qv[i] * kp;
        }
    }
    __syncthreads();

    float rs[4] = {0.0f, 0.0f, 0.0f, 0.0f};
    for (int j = 0; j < 64; ++j) {
        const float4 ve = *(const float4*)&Vs[j][tx * 4];
        const float vv[4] = {ve.x, ve.y, ve.z, ve.w};
#pragma unroll
        for (int i = 0; i < 4; ++i) {
            const float aij = As[ty * 4 + i][j];
            rs[i] += aij;
            num[i][0] += aij * vv[0];
            num[i][1] += aij * vv[1];
            num[i][2] += aij * vv[2];
            num[i][3] += aij * vv[3];
        }
    }

#pragma unroll
    for (int i = 0; i < 4; ++i) {
        const float dn = den[i] + rs[i];
        const float r  = 1.0f / dn;
        const int srow = c * CHUNK + ty * 4 + i;
        ushort4 o;
        o.x = bf16r(num[i][0] * r); o.y = bf16r(num[i][1] * r);
        o.z = bf16r(num[i][2] * r); o.w = bf16r(num[i][3] * r);
        *(ushort4*)(out_pre + (size_t)srow * DM + h * DH + tx * 4) = o;
    }
}

extern "C" void kernel_launch(void* const* d_in, const int* in_sizes, int n_in,
                              void* d_out, int out_size, void* d_ws, size_t ws_size,
                              hipStream_t stream)
{
    const float* x    = (const float*)d_in[0];
    const float* Wq   = (const float*)d_in[1];
    const float* bq   = (const float*)d_in[2];
    const float* Wk   = (const float*)d_in[3];
    const float* bk   = (const float*)d_in[4];
    const float* Wv   = (const float*)d_in[5];
    const float* bv   = (const float*)d_in[6];
    const float* Wo   = (const float*)d_in[7];
    const float* bo   = (const float*)d_in[8];
    const float* beta = (const float*)d_in[9];
    float* out = (float*)d_out;

    float*  q_ws  = (float*)d_ws;                          // 3 x 2M floats (q|k|v)
    float*  k_ws  = q_ws + (size_t)NH * S_LEN * DH;
    float*  v_ws  = k_ws + (size_t)NH * S_LEN * DH;
    float*  st    = v_ws + (size_t)NH * S_LEN * DH;        // 16*32*4160 floats
    ushort* x_bf  = (ushort*)(st + (size_t)NH * NCH * ST_STRIDE);   // 2M bf16
    ushort* w_bf  = x_bf + (size_t)S_LEN * DM;                      // 4 x 1M bf16 (Wq|Wk|Wv|Wo)
    ushort* op_bf = w_bf + (size_t)4 * DM * DM;                     // 2M bf16

    const ushort* wo_bf = w_bf + (size_t)3 * DM * DM;

    cast_x_kernel<<<(S_LEN * DM) / 1024, 256, 0, stream>>>(x, x_bf);
    cast_w_kernel<<<dim3((DM * DM) / 1024, 4), 256, 0, stream>>>(Wq, Wk, Wv, Wo, w_bf);

    qkv_gemm_kernel<<<384, 512, 0, stream>>>(x_bf, w_bf, bq, bk, bv, beta, q_ws);

    chunk_state_kernel<<<dim3(NCH, NH), 256, 0, stream>>>(k_ws, v_ws, st);
    scan_kernel<<<dim3(ST_STRIDE / 64, NH), 64, 0, stream>>>(st);
    attn_out_kernel<<<dim3(NCH, NH), 256, 0, stream>>>(q_ws, k_ws, v_ws, st, op_bf);

    o_gemm_kernel<<<256, 256, 0, stream>>>(op_bf, wo_bf, bo, out);
}